// Round 11
// baseline (22.731 us; speedup 1.0000x reference)
//
#include <hip/hip_runtime.h>

#define BS 2048
#define DIM 256
#define MARGIN_F 0.3f

typedef __attribute__((ext_vector_type(4))) float f32x4;
typedef __attribute__((ext_vector_type(2))) __fp16 fp16x2;   // cvt_pkrtz return type
typedef __attribute__((ext_vector_type(8))) _Float16 f16x8;  // MFMA operand type

// Async global->LDS direct load, 16 B per lane (global_load_lds_dwordx4).
__device__ __forceinline__ void gload_lds16(const void* g, void* l) {
    __builtin_amdgcn_global_load_lds((const __attribute__((address_space(1))) void*)g,
                                     (__attribute__((address_space(3))) void*)l,
                                     16, 0, 0);
}

// Kernel 1: fused norms + fp32->fp16 pre-convert with PRE-SWIZZLED layout
// (verbatim r7, verified absmax 0.0). Also zeroes d_out (stream-ordered
// before tl_gemm's atomics).
__global__ __launch_bounds__(256) void tl_prep(const float* __restrict__ sketch,
                                               const float* __restrict__ photo,
                                               float* __restrict__ sn,
                                               float* __restrict__ pn,
                                               float* __restrict__ pos,
                                               _Float16* __restrict__ hs,
                                               _Float16* __restrict__ hp,
                                               float* __restrict__ out) {
    const int t = threadIdx.x;
    const int w = t >> 6, lane = t & 63;
    const int row = blockIdx.x * 4 + w;
    const float4 s4 = *reinterpret_cast<const float4*>(&sketch[(size_t)row * DIM + lane * 4]);
    const float4 p4 = *reinterpret_cast<const float4*>(&photo [(size_t)row * DIM + lane * 4]);

    float vs = s4.x * s4.x + s4.y * s4.y + s4.z * s4.z + s4.w * s4.w;
    float vp = p4.x * p4.x + p4.y * p4.y + p4.z * p4.z + p4.w * p4.w;
    float dx = s4.x - p4.x, dy = s4.y - p4.y, dz = s4.z - p4.z, dw = s4.w - p4.w;
    float vd = dx * dx + dy * dy + dz * dz + dw * dw;
    #pragma unroll
    for (int off = 32; off > 0; off >>= 1) {
        vs += __shfl_down(vs, off);
        vp += __shfl_down(vp, off);
        vd += __shfl_down(vd, off);
    }
    if (lane == 0) { sn[row] = vs; pn[row] = vp; pos[row] = sqrtf(vd); }

    union { fp16x2 h2[2]; uint2 u; } cs, cp;
    cs.h2[0] = __builtin_amdgcn_cvt_pkrtz(s4.x, s4.y);
    cs.h2[1] = __builtin_amdgcn_cvt_pkrtz(s4.z, s4.w);
    cp.h2[0] = __builtin_amdgcn_cvt_pkrtz(p4.x, p4.y);
    cp.h2[1] = __builtin_amdgcn_cvt_pkrtz(p4.z, p4.w);
    const int qg = lane >> 1;
    const int pg = (qg & 24) | ((qg & 7) ^ (row & 7));
    const size_t dsth = (size_t)row * DIM + pg * 8 + (lane & 1) * 4;
    *reinterpret_cast<uint2*>(&hs[dsth]) = cs.u;
    *reinterpret_cast<uint2*>(&hp[dsth]) = cp.u;

    if (blockIdx.x == 0 && t == 0) out[0] = 0.0f;
}

// Kernel 2: fp16 MFMA cross-GEMM, 128x256 tile per 512-thread block (8 waves,
// each a 64x64 sub-tile = 4x4 frags of 16x16x32_f16). K staged per 64-half
// window via global_load_lds (linear LDS dest, pre-swizzled global source,
// XOR-deswizzled fragment reads -- verbatim r7 addressing, verified).
// Full unroll of all 4 windows (no #pragma unroll 1 -- that serialized r9/r10).
// Block result: ONE pre-scaled atomicAdd (chain depth 128).
__global__ __launch_bounds__(512, 2) void tl_gemm(const _Float16* __restrict__ hp,
                                                  const _Float16* __restrict__ hs,
                                                  const float* __restrict__ sn,
                                                  const float* __restrict__ pn,
                                                  const float* __restrict__ pos,
                                                  float* __restrict__ out) {
    __shared__ _Float16 As[128][64];   // photo rows (i), one 64-half K-window
    __shared__ _Float16 Bs[256][64];   // sketch rows (j)

    const int t = threadIdx.x;
    const int i0 = blockIdx.y * 128;   // 16 i-tiles
    const int j0 = blockIdx.x * 256;   // 8 j-tiles
    const int w = t >> 6, lane = t & 63;
    const int wr = (w >> 2) * 64;      // wave row offset (2 row-blocks)
    const int wc = (w & 3) * 64;       // wave col offset (4 col-blocks)
    const int r16 = lane & 15, g = lane >> 4;

    f32x4 acc[4][4] = {};

    // Staging geometry: per 1KB instr, lane -> row lane>>3, 16B chunk lane&7.
    // Wave w stages A rows [w*16, w*16+16) (2 instrs) and B rows [w*32, w*32+32) (4 instrs).
    const int sch = lane & 7;
    const _Float16* gA = &hp[(size_t)(i0 + w * 16 + (lane >> 3)) * DIM + sch * 8];
    const _Float16* gB = &hs[(size_t)(j0 + w * 32 + (lane >> 3)) * DIM + sch * 8];
    _Float16* lA0 = &As[w * 16][0];
    _Float16* lA1 = &As[w * 16 + 8][0];
    _Float16* lB0 = &Bs[w * 32][0];
    _Float16* lB1 = &Bs[w * 32 + 8][0];
    _Float16* lB2 = &Bs[w * 32 + 16][0];
    _Float16* lB3 = &Bs[w * 32 + 24][0];

    const int xa = r16 & 7;            // deswizzle XOR (row&7 == r16&7: offsets mult of 8)

    #pragma unroll
    for (int kw = 0; kw < 4; ++kw) {
        const int koff = kw * 64;      // halves
        gload_lds16(gA + koff, lA0);
        gload_lds16(gA + 8 * DIM + koff, lA1);
        gload_lds16(gB + koff, lB0);
        gload_lds16(gB + 8 * DIM + koff, lB1);
        gload_lds16(gB + 16 * DIM + koff, lB2);
        gload_lds16(gB + 24 * DIM + koff, lB3);
        __syncthreads();
        #pragma unroll
        for (int ks = 0; ks < 2; ++ks) {
            const int q8 = ((ks * 4 + g) ^ xa) * 8;
            f16x8 af[4], bf[4];
            #pragma unroll
            for (int m = 0; m < 4; ++m)
                af[m] = *reinterpret_cast<const f16x8*>(&As[wr + m * 16 + r16][q8]);
            #pragma unroll
            for (int n = 0; n < 4; ++n)
                bf[n] = *reinterpret_cast<const f16x8*>(&Bs[wc + n * 16 + r16][q8]);
            #pragma unroll
            for (int m = 0; m < 4; ++m)
                #pragma unroll
                for (int n = 0; n < 4; ++n)
                    acc[m][n] = __builtin_amdgcn_mfma_f32_16x16x32_f16(af[m], bf[n], acc[m][n], 0, 0, 0);
        }
        __syncthreads();
    }

    // Fused epilogue (verified layout): col = lane&15 (j), row = g*4 + reg (i).
    float partial = 0.0f;
    #pragma unroll
    for (int n = 0; n < 4; ++n) {
        const int j = j0 + wc + n * 16 + r16;
        const float snj = sn[j];
        const float posj = pos[j];
        #pragma unroll
        for (int m = 0; m < 4; ++m) {
            const int ibase = i0 + wr + m * 16 + g * 4;
            #pragma unroll
            for (int r = 0; r < 4; ++r) {
                const int i = ibase + r;
                const float c = acc[m][n][r];
                float neg2 = fmaxf(pn[i] + snj - 2.0f * c, 0.0f);
                float tl = posj - sqrtf(neg2) + MARGIN_F;
                partial += (i != j) ? fmaxf(tl, 0.0f) : 0.0f;
            }
        }
    }

    // Wave reduce -> block reduce -> one pre-scaled atomicAdd per block.
    #pragma unroll
    for (int off = 32; off > 0; off >>= 1) partial += __shfl_down(partial, off);
    __shared__ float lsum[8];
    if (lane == 0) lsum[w] = partial;
    __syncthreads();
    if (t == 0) {
        float s = 0.0f;
        #pragma unroll
        for (int q = 0; q < 8; ++q) s += lsum[q];
        atomicAdd(out, s * (1.0f / ((float)BS * (float)BS)));
    }
}

extern "C" void kernel_launch(void* const* d_in, const int* in_sizes, int n_in,
                              void* d_out, int out_size, void* d_ws, size_t ws_size,
                              hipStream_t stream) {
    const float* sketch = (const float*)d_in[0];
    const float* photo  = (const float*)d_in[1];
    float* out = (float*)d_out;

    float* sn  = (float*)d_ws;              // BS floats
    float* pn  = sn + BS;                   // BS floats
    float* pos = pn + BS;                   // BS floats
    _Float16* hp = (_Float16*)(pos + BS);   // BS*DIM halves (photo fp16, swizzled)
    _Float16* hs = hp + (size_t)BS * DIM;   // BS*DIM halves (sketch fp16, swizzled)

    // tl_prep zeroes d_out (runs before tl_gemm's atomics in stream order).
    tl_prep<<<dim3(BS / 4), dim3(256), 0, stream>>>(sketch, photo, sn, pn, pos, hs, hp, out);

    dim3 grid(BS / 256, BS / 128);   // 8 x 16 = 128 blocks, 512 threads each
    tl_gemm<<<grid, dim3(512), 0, stream>>>(hp, hs, sn, pn, pos, out);
}

// Round 12
// 19.604 us; speedup vs baseline: 1.1595x; 1.1595x over previous
//
#include <hip/hip_runtime.h>

#define BS 2048
#define DIM 256
#define MARGIN_F 0.3f

typedef __attribute__((ext_vector_type(4))) float f32x4;
typedef __attribute__((ext_vector_type(2))) __fp16 fp16x2;   // cvt_pkrtz return type
typedef __attribute__((ext_vector_type(8))) _Float16 f16x8;  // MFMA operand type

// Async global->LDS direct load, 16 B per lane (global_load_lds_dwordx4).
__device__ __forceinline__ void gload_lds16(const void* g, void* l) {
    __builtin_amdgcn_global_load_lds((const __attribute__((address_space(1))) void*)g,
                                     (__attribute__((address_space(3))) void*)l,
                                     16, 0, 0);
}

// Kernel 1: fused norms + fp32->fp16 pre-convert with PRE-SWIZZLED layout
// (verbatim r7/r10, verified absmax 0.0).
__global__ __launch_bounds__(256) void tl_prep(const float* __restrict__ sketch,
                                               const float* __restrict__ photo,
                                               float* __restrict__ sn,
                                               float* __restrict__ pn,
                                               float* __restrict__ pos,
                                               _Float16* __restrict__ hs,
                                               _Float16* __restrict__ hp) {
    const int t = threadIdx.x;
    const int w = t >> 6, lane = t & 63;
    const int row = blockIdx.x * 4 + w;
    const float4 s4 = *reinterpret_cast<const float4*>(&sketch[(size_t)row * DIM + lane * 4]);
    const float4 p4 = *reinterpret_cast<const float4*>(&photo [(size_t)row * DIM + lane * 4]);

    float vs = s4.x * s4.x + s4.y * s4.y + s4.z * s4.z + s4.w * s4.w;
    float vp = p4.x * p4.x + p4.y * p4.y + p4.z * p4.z + p4.w * p4.w;
    float dx = s4.x - p4.x, dy = s4.y - p4.y, dz = s4.z - p4.z, dw = s4.w - p4.w;
    float vd = dx * dx + dy * dy + dz * dz + dw * dw;
    #pragma unroll
    for (int off = 32; off > 0; off >>= 1) {
        vs += __shfl_down(vs, off);
        vp += __shfl_down(vp, off);
        vd += __shfl_down(vd, off);
    }
    if (lane == 0) { sn[row] = vs; pn[row] = vp; pos[row] = sqrtf(vd); }

    union { fp16x2 h2[2]; uint2 u; } cs, cp;
    cs.h2[0] = __builtin_amdgcn_cvt_pkrtz(s4.x, s4.y);
    cs.h2[1] = __builtin_amdgcn_cvt_pkrtz(s4.z, s4.w);
    cp.h2[0] = __builtin_amdgcn_cvt_pkrtz(p4.x, p4.y);
    cp.h2[1] = __builtin_amdgcn_cvt_pkrtz(p4.z, p4.w);
    const int qg = lane >> 1;
    const int pg = (qg & 24) | ((qg & 7) ^ (row & 7));
    const size_t dsth = (size_t)row * DIM + pg * 8 + (lane & 1) * 4;
    *reinterpret_cast<uint2*>(&hs[dsth]) = cs.u;
    *reinterpret_cast<uint2*>(&hp[dsth]) = cp.u;
}

// Kernel 2: r10's gemm with (a) ALL 4 K-windows staged up front -> ONE vmcnt
// drain, zero mid-loop global stalls; (b) XCD-chunked tile swizzle so blocks
// sharing panels land on the same XCD L2. Addressing verbatim r10 (verified).
__global__ __launch_bounds__(256) void tl_gemm(const _Float16* __restrict__ hp,
                                               const _Float16* __restrict__ hs,
                                               const float* __restrict__ sn,
                                               const float* __restrict__ pn,
                                               const float* __restrict__ pos,
                                               float* __restrict__ partials) {
    __shared__ _Float16 As[4][64][64];   // [window][row][64 halves] photo (i)
    __shared__ _Float16 Bs[4][64][64];   // sketch (j)

    // XCD-chunked swizzle (bijective: 1024 blocks = 8 XCDs x 128 slots).
    // HW maps block b -> XCD (b & 7); give XCD x an 8x16 tile patch.
    const int b = blockIdx.x;
    const int xcd = b & 7, slot = b >> 3;
    const int by = (xcd & 3) * 8 + (slot >> 4);    // i-panel 0..31
    const int bx = (xcd >> 2) * 16 + (slot & 15);  // j-panel 0..31

    const int t = threadIdx.x;
    const int i0 = by * 64;
    const int j0 = bx * 64;
    const int w = t >> 6, lane = t & 63;
    const int wr = (w >> 1) * 32;
    const int wc = (w & 1) * 32;
    const int r16 = lane & 15, g = lane >> 4;

    f32x4 acc00 = {}, acc01 = {}, acc10 = {}, acc11 = {};

    // Staging: per 1KB instr, lane -> row lane>>3, 16B chunk lane&7 (r10 verbatim).
    const int srow = w * 16 + (lane >> 3);
    const int sch  = lane & 7;
    const _Float16* gA0 = &hp[(size_t)(i0 + srow) * DIM + sch * 8];
    const _Float16* gB0 = &hs[(size_t)(j0 + srow) * DIM + sch * 8];

    #pragma unroll
    for (int kw = 0; kw < 4; ++kw) {
        const int koff = kw * 64;
        gload_lds16(gA0 + koff,           &As[kw][w * 16][0]);
        gload_lds16(gA0 + 8 * DIM + koff, &As[kw][w * 16 + 8][0]);
        gload_lds16(gB0 + koff,           &Bs[kw][w * 16][0]);
        gload_lds16(gB0 + 8 * DIM + koff, &Bs[kw][w * 16 + 8][0]);
    }
    __syncthreads();   // the ONE global drain

    const int xa = r16 & 7;   // deswizzle XOR (row&7 == r16&7: offsets mult of 8)
    #pragma unroll
    for (int kw = 0; kw < 4; ++kw) {
        #pragma unroll
        for (int ks = 0; ks < 2; ++ks) {
            const int q8 = ((ks * 4 + g) ^ xa) * 8;
            f16x8 a0 = *reinterpret_cast<const f16x8*>(&As[kw][wr + r16][q8]);
            f16x8 a1 = *reinterpret_cast<const f16x8*>(&As[kw][wr + 16 + r16][q8]);
            f16x8 b0 = *reinterpret_cast<const f16x8*>(&Bs[kw][wc + r16][q8]);
            f16x8 b1 = *reinterpret_cast<const f16x8*>(&Bs[kw][wc + 16 + r16][q8]);
            acc00 = __builtin_amdgcn_mfma_f32_16x16x32_f16(a0, b0, acc00, 0, 0, 0);
            acc01 = __builtin_amdgcn_mfma_f32_16x16x32_f16(a0, b1, acc01, 0, 0, 0);
            acc10 = __builtin_amdgcn_mfma_f32_16x16x32_f16(a1, b0, acc10, 0, 0, 0);
            acc11 = __builtin_amdgcn_mfma_f32_16x16x32_f16(a1, b1, acc11, 0, 0, 0);
        }
    }

    // Fused epilogue (verified layout): col = lane&15 (j), row = g*4 + reg (i).
    const int jl = r16;
    const int rl = g * 4;
    float partial = 0.0f;

    #pragma unroll
    for (int n = 0; n < 2; ++n) {
        const int j = j0 + wc + n * 16 + jl;
        const float snj = sn[j];
        const float posj = pos[j];
        const f32x4 cn0 = (n == 0) ? acc00 : acc01;
        const f32x4 cn1 = (n == 0) ? acc10 : acc11;
        #pragma unroll
        for (int m = 0; m < 2; ++m) {
            const int ibase = i0 + wr + m * 16 + rl;
            const f32x4 cv = (m == 0) ? cn0 : cn1;
            #pragma unroll
            for (int r = 0; r < 4; ++r) {
                const int i = ibase + r;
                const float c = cv[r];
                float neg2 = fmaxf(pn[i] + snj - 2.0f * c, 0.0f);
                float tl = posj - sqrtf(neg2) + MARGIN_F;
                partial += (i != j) ? fmaxf(tl, 0.0f) : 0.0f;
            }
        }
    }

    #pragma unroll
    for (int off = 32; off > 0; off >>= 1) partial += __shfl_down(partial, off);
    __shared__ float lsum[4];
    if (lane == 0) lsum[w] = partial;
    __syncthreads();
    if (t == 0)
        partials[b] = lsum[0] + lsum[1] + lsum[2] + lsum[3];
}

// Kernel 3: reduce 1024 block partials -> out[0] (r10 verbatim).
__global__ __launch_bounds__(256) void tl_reduce(const float* __restrict__ partials,
                                                 float* __restrict__ out) {
    const int t = threadIdx.x;
    const float4 v = reinterpret_cast<const float4*>(partials)[t];
    float s = v.x + v.y + v.z + v.w;
    #pragma unroll
    for (int off = 32; off > 0; off >>= 1) s += __shfl_down(s, off);
    __shared__ float lsum[4];
    const int w = t >> 6, lane = t & 63;
    if (lane == 0) lsum[w] = s;
    __syncthreads();
    if (t == 0)
        out[0] = (lsum[0] + lsum[1] + lsum[2] + lsum[3]) * (1.0f / ((float)BS * (float)BS));
}

extern "C" void kernel_launch(void* const* d_in, const int* in_sizes, int n_in,
                              void* d_out, int out_size, void* d_ws, size_t ws_size,
                              hipStream_t stream) {
    const float* sketch = (const float*)d_in[0];
    const float* photo  = (const float*)d_in[1];
    float* out = (float*)d_out;

    float* sn  = (float*)d_ws;              // BS floats
    float* pn  = sn + BS;                   // BS floats
    float* pos = pn + BS;                   // BS floats
    _Float16* hp = (_Float16*)(pos + BS);   // BS*DIM halves (photo fp16, swizzled)
    _Float16* hs = hp + (size_t)BS * DIM;   // BS*DIM halves (sketch fp16, swizzled)
    float* partials = (float*)(hs + (size_t)BS * DIM);  // 1024 floats

    tl_prep<<<dim3(BS / 4), dim3(256), 0, stream>>>(sketch, photo, sn, pn, pos, hs, hp);

    tl_gemm<<<dim3(1024), dim3(256), 0, stream>>>(hp, hs, sn, pn, pos, partials);

    tl_reduce<<<dim3(1), dim3(256), 0, stream>>>(partials, out);
}